// Round 1
// baseline (3072.804 us; speedup 1.0000x reference)
//
#include <hip/hip_runtime.h>

// ConvLSTM: B=8, T=16, CIN=16, HID=64, H=W=64, K=3 'SAME'.
// Strategy: 16 sequential per-timestep kernels (spatial dependency via 3x3 conv
// on h forces a global sync per step). h/c state ping-pongs between ws and d_out
// (d_out == exactly one h|c buffer, and step 15 is odd so it lands in d_out).
// fp32 direct conv, weights pre-transposed to [c][ky][kx][gate][o] for float4
// weight loads broadcast across 16 output channels groups.

#define B_ 8
#define T_ 16
#define CIN_ 16
#define HID_ 64
#define H_ 64
#define W_ 64
#define CTOT_ 80            // CIN + HID
#define HW_ (H_*W_)
#define CSTRIDE_ (B_*HID_*HW_)   // 2097152 floats: offset of c within an h|c buffer

__device__ __forceinline__ float sigmoidf_(float v){ return 1.0f/(1.0f + __expf(-v)); }
__device__ __forceinline__ float tanh_fast(float v){ return 2.0f/(1.0f + __expf(-2.0f*v)) - 1.0f; }

// Wt layout: idx = (((c*3+ky)*3+kx)*3 + g)*64 + o   (g: 0=f,1=i,2=c-gate)
// Wot layout: c*64 + o
__global__ void prep_weights(const float* __restrict__ Wf, const float* __restrict__ Wi,
                             const float* __restrict__ Wc, const float* __restrict__ Wo,
                             float* __restrict__ Wt, float* __restrict__ Wot){
    int idx = blockIdx.x*256 + threadIdx.x;
    if (idx < CTOT_*3*3*3*HID_){
        int o = idx & 63;
        int r = idx >> 6;
        int g  = r % 3; r /= 3;
        int kx = r % 3; r /= 3;
        int ky = r % 3; int c = r / 3;
        const float* W = (g==0)? Wf : (g==1)? Wi : Wc;
        Wt[idx] = W[((o*CTOT_ + c)*3 + ky)*3 + kx];
    }
    if (idx < CTOT_*HID_){
        int o = idx & 63; int c = idx >> 6;
        Wot[idx] = Wo[o*CTOT_ + c];
    }
}

// One block = one (batch, output row). 256 threads = 16 x-groups x 16 oc-groups.
// Thread: 4 consecutive x pixels x 4 consecutive out-channels, all 4 gates.
__global__ __launch_bounds__(256, 2) void lstm_step(
    const float* __restrict__ x,
    const float* __restrict__ hc_in,
    float* __restrict__ hc_out,
    const float* __restrict__ Wt,
    const float* __restrict__ Wot,
    const float* __restrict__ bf, const float* __restrict__ bi,
    const float* __restrict__ bc, const float* __restrict__ bo,
    int t, int first)
{
    const int y   = blockIdx.x;
    const int b   = blockIdx.y;
    const int tid = threadIdx.x;
    const int xg  = tid & 15;
    const int og  = tid >> 4;
    const int x0  = xg * 4;
    const int oc0 = og * 4;

    float accf[4][4] = {};
    float acci[4][4] = {};
    float accg[4][4] = {};
    float acco[4][4] = {};

    const float* xt = x + ((size_t)b*T_ + t) * CIN_ * HW_;
    const float* hb = hc_in + (size_t)b * HID_ * HW_;

    const int cmax = first ? CIN_ : CTOT_;   // h==0 at t==0: skip its channels
    for (int c = 0; c < cmax; ++c){
        const float* chan = (c < CIN_) ? (xt + (size_t)c*HW_)
                                       : (hb + (size_t)(c-CIN_)*HW_);
        #pragma unroll
        for (int ky = 0; ky < 3; ++ky){
            const int yy = y + ky - 1;
            if (yy < 0 || yy >= H_) continue;     // SAME padding: zero rows skipped
            const float* rp = chan + yy*W_ + x0;
            float in6[6];
            in6[0] = (x0 > 0) ? rp[-1] : 0.0f;
            float4 v = *(const float4*)rp;         // x0..x0+3 always in-bounds, 16B aligned
            in6[1]=v.x; in6[2]=v.y; in6[3]=v.z; in6[4]=v.w;
            in6[5] = (x0 + 4 < W_) ? rp[4] : 0.0f;

            const float* wbase = Wt + (c*3 + ky)*576 + oc0;
            #pragma unroll
            for (int kx = 0; kx < 3; ++kx){
                float4 wf4 = *(const float4*)(wbase + kx*192 + 0);
                float4 wi4 = *(const float4*)(wbase + kx*192 + 64);
                float4 wc4 = *(const float4*)(wbase + kx*192 + 128);
                #pragma unroll
                for (int px = 0; px < 4; ++px){
                    float iv = in6[px + kx];
                    accf[px][0] += iv*wf4.x; accf[px][1] += iv*wf4.y; accf[px][2] += iv*wf4.z; accf[px][3] += iv*wf4.w;
                    acci[px][0] += iv*wi4.x; acci[px][1] += iv*wi4.y; acci[px][2] += iv*wi4.z; acci[px][3] += iv*wi4.w;
                    accg[px][0] += iv*wc4.x; accg[px][1] += iv*wc4.y; accg[px][2] += iv*wc4.z; accg[px][3] += iv*wc4.w;
                }
            }
            if (ky == 1){   // channel-linear o-gate uses center pixel only
                float4 wo4 = *(const float4*)(Wot + c*HID_ + oc0);
                #pragma unroll
                for (int px = 0; px < 4; ++px){
                    float iv = in6[px + 1];
                    acco[px][0] += iv*wo4.x; acco[px][1] += iv*wo4.y; acco[px][2] += iv*wo4.z; acco[px][3] += iv*wo4.w;
                }
            }
        }
    }

    float4 vb;
    vb = *(const float4*)(bf + oc0); float bfa[4] = {vb.x, vb.y, vb.z, vb.w};
    vb = *(const float4*)(bi + oc0); float bia[4] = {vb.x, vb.y, vb.z, vb.w};
    vb = *(const float4*)(bc + oc0); float bca[4] = {vb.x, vb.y, vb.z, vb.w};
    vb = *(const float4*)(bo + oc0); float boa[4] = {vb.x, vb.y, vb.z, vb.w};

    const size_t base = ((size_t)(b*HID_ + oc0)*H_ + y)*W_ + x0;
    #pragma unroll
    for (int oc_ = 0; oc_ < 4; ++oc_){
        const size_t off = base + (size_t)oc_*HW_;
        float cprev[4] = {0.0f, 0.0f, 0.0f, 0.0f};
        if (!first){
            float4 cold = *(const float4*)(hc_in + CSTRIDE_ + off);
            cprev[0]=cold.x; cprev[1]=cold.y; cprev[2]=cold.z; cprev[3]=cold.w;
        }
        float hn[4], cn[4];
        #pragma unroll
        for (int px = 0; px < 4; ++px){
            float fv = sigmoidf_(accf[px][oc_] + bfa[oc_]);
            float iv = sigmoidf_(acci[px][oc_] + bia[oc_]);
            float gv = tanh_fast(accg[px][oc_] + bca[oc_]);
            float ov = sigmoidf_(acco[px][oc_] + boa[oc_]);
            float cv = cprev[px]*fv + iv*gv;
            cn[px] = cv;
            hn[px] = tanh_fast(cv)*ov;
        }
        *(float4*)(hc_out + off)            = make_float4(hn[0],hn[1],hn[2],hn[3]);
        *(float4*)(hc_out + CSTRIDE_ + off) = make_float4(cn[0],cn[1],cn[2],cn[3]);
    }
}

extern "C" void kernel_launch(void* const* d_in, const int* in_sizes, int n_in,
                              void* d_out, int out_size, void* d_ws, size_t ws_size,
                              hipStream_t stream){
    const float* x  = (const float*)d_in[0];
    const float* Wf = (const float*)d_in[1];
    const float* bf = (const float*)d_in[2];
    const float* Wi = (const float*)d_in[3];
    const float* bi = (const float*)d_in[4];
    const float* Wc = (const float*)d_in[5];
    const float* bc = (const float*)d_in[6];
    const float* Wo = (const float*)d_in[7];
    const float* bo = (const float*)d_in[8];

    // ws layout: Wt (138240 f) | Wot (5120 f) | state buffer h|c (4194304 f)
    float* Wt   = (float*)d_ws;
    float* Wot  = Wt + 138240;
    float* stA  = Wot + 5120;
    float* bufB = (float*)d_out;   // d_out doubles as the odd-step state buffer

    prep_weights<<<dim3(540), dim3(256), 0, stream>>>(Wf, Wi, Wc, Wo, Wt, Wot);

    dim3 grid(H_, B_);
    for (int t = 0; t < T_; ++t){
        float* out      = (t & 1) ? bufB : stA;   // t=15 (odd) -> d_out: final hT|cT
        const float* in = (t & 1) ? stA  : bufB;  // t=0 never reads (first=1)
        lstm_step<<<grid, dim3(256), 0, stream>>>(x, in, out, Wt, Wot,
                                                  bf, bi, bc, bo, t, (t==0)?1:0);
    }
}

// Round 2
// 550.194 us; speedup vs baseline: 5.5849x; 5.5849x over previous
//
#include <hip/hip_runtime.h>

// ConvLSTM B=8,T=16,CIN=16,HID=64,H=W=64,K=3 'SAME' — bf16 MFMA implicit GEMM.
// Per step: Y[64px x 256n] per (b,y) block; K = 9 taps x 96 padded channels.
// n = g*64+o: g in {f,i,c-gate}, g==3 = channel-linear o-gate (center tap only).
// Wave w owns o in [16w,16w+16); its 4 n-frags are the 4 gates -> wave-local epilogue.
// A staged in LDS channel-last with zero borders (SAME padding for free);
// B pre-swizzled to MFMA fragment order in global (prep kernel), loaded dwordx4.
// h recirculates as bf16 channel-last; c stays fp32 (state error containment).

#define B_ 8
#define T_ 16
#define CIN_ 16
#define HID_ 64
#define H_ 64
#define W_ 64
#define HW_ (H_*W_)
#define CTOT_ 80
#define XS_ROW 66
#define XS_CH 104                       // 96 used + 8 pad (bank de-stride, 16B align kept)
#define XS_SIZE (3*XS_ROW*XS_CH)        // 20592 halfwords = 41184 B
#define CSTRIDE_ (B_*HID_*HW_)          // 2097152

typedef __attribute__((ext_vector_type(8))) short short8;
typedef __attribute__((ext_vector_type(4))) float f32x4;

__device__ __forceinline__ unsigned short f2bf(float f){
    unsigned u = __float_as_uint(f);
    u = (u + 0x7FFFu + ((u >> 16) & 1u)) >> 16;   // RNE
    return (unsigned short)u;
}
__device__ __forceinline__ float sigm_(float v){ return 1.0f/(1.0f + __expf(-v)); }
__device__ __forceinline__ float tanh_(float v){ return 2.0f/(1.0f + __expf(-2.0f*v)) - 1.0f; }

// Wfrag layout: [tap 9][cc 3][ng 16] frags; frag = [lane 64][j 8] halfwords (512 hw).
// Element: n = ng*16 + (lane&15) -> g=n>>6, o=n&63; k-channel c = cc*32 + (lane>>4)*8 + j.
__global__ void prep_wfrag(const float* __restrict__ Wf, const float* __restrict__ Wi,
                           const float* __restrict__ Wc, const float* __restrict__ Wo,
                           unsigned short* __restrict__ Wfrag){
    int idx = blockIdx.x*256 + threadIdx.x;          // grid exact: 864*256 = 221184
    int j    = idx & 7;
    int lane = (idx >> 3) & 63;
    int frag = idx >> 9;                             // 0..431
    int ng = frag & 15;
    int tc = frag >> 4;                              // 0..26
    int cc = tc % 3, tap = tc / 3;
    int n = ng*16 + (lane & 15);
    int g = n >> 6, o = n & 63;
    int c = cc*32 + ((lane >> 4) << 3) + j;
    int ky = tap / 3, kx = tap % 3;
    float v = 0.0f;
    if (c < CTOT_){
        if (g == 0)      v = Wf[((o*CTOT_ + c)*3 + ky)*3 + kx];
        else if (g == 1) v = Wi[((o*CTOT_ + c)*3 + ky)*3 + kx];
        else if (g == 2) v = Wc[((o*CTOT_ + c)*3 + ky)*3 + kx];
        else             v = (tap == 4) ? Wo[o*CTOT_ + c] : 0.0f;
    }
    Wfrag[idx] = f2bf(v);
}

__global__ __launch_bounds__(256, 2) void lstm_step_mfma(
    const float* __restrict__ x,                     // [8][16][16][64][64] fp32
    const float* __restrict__ c_in,                  // [8][64][64][64] fp32
    const unsigned short* __restrict__ hbf_in,       // [8][64][64][64] bf16 ch-last
    const unsigned short* __restrict__ Wfrag,
    float* __restrict__ c_out,
    unsigned short* __restrict__ hbf_out,
    float* __restrict__ h_out,                       // fp32 std layout, written iff last
    const float* __restrict__ bfp, const float* __restrict__ bip,
    const float* __restrict__ bcp, const float* __restrict__ bop,
    int t, int first, int last)
{
    __shared__ __align__(16) unsigned short Xs[XS_SIZE];
    const int y   = blockIdx.x;
    const int b   = blockIdx.y;
    const int tid = threadIdx.x;
    const int lane = tid & 63;
    const int w    = tid >> 6;
    const int l15  = lane & 15;
    const int q    = lane >> 4;

    // ---- zero LDS (borders / padded channels / OOB rows become SAME-pad zeros)
    uint4 z4; z4.x = z4.y = z4.z = z4.w = 0u;
    for (int i = tid; i < XS_SIZE/8; i += 256) ((uint4*)Xs)[i] = z4;
    __syncthreads();

    // ---- stage x channels (0..15): coalesced fp32 row loads, scalar bf16 writes
    {
        const float* xt = x + (((size_t)b*T_ + t)*CIN_)*HW_;
        const int xl = tid & 63;
        for (int tk = w; tk < 3*CIN_; tk += 4){
            int row = tk % 3, c = tk / 3;
            int yy = y + row - 1;
            if (yy >= 0 && yy < H_){
                float v = xt[c*HW_ + yy*W_ + xl];
                Xs[(row*XS_ROW + xl + 1)*XS_CH + c] = f2bf(v);
            }
        }
    }
    // ---- stage h channels (16..79): bf16 channel-last, 16B vector copies
    if (!first){
        for (int i = tid; i < 3*64*8; i += 256){
            int ch8 = i & 7;
            int px  = (i >> 3) & 63;
            int row = i >> 9;
            int yy = y + row - 1;
            if (yy >= 0 && yy < H_){
                uint4 v = *(const uint4*)(hbf_in + (((size_t)b*H_ + yy)*W_ + px)*HID_ + ch8*8);
                *(uint4*)(Xs + (row*XS_ROW + px + 1)*XS_CH + CIN_ + ch8*8) = v;
            }
        }
    }
    __syncthreads();

    // ---- K-loop: 3 channel-chunks x 9 taps, 16 MFMA each (4 gates x 4 m-frags)
    f32x4 acc[4][4];
    #pragma unroll
    for (int g = 0; g < 4; ++g)
        #pragma unroll
        for (int mf = 0; mf < 4; ++mf)
            acc[g][mf] = (f32x4)0.0f;

    const int ccmax = first ? 1 : 3;     // t==0: h==0, only x channels contribute
    for (int cc = 0; cc < ccmax; ++cc){
        #pragma unroll
        for (int tap = 0; tap < 9; ++tap){
            const int ky = tap / 3, kx = tap % 3;
            short8 a[4];
            #pragma unroll
            for (int mf = 0; mf < 4; ++mf){
                const unsigned short* ap =
                    Xs + ((size_t)(ky*XS_ROW + mf*16 + l15 + kx))*XS_CH + cc*32 + q*8;
                a[mf] = *(const short8*)ap;
            }
            short8 bb[4];
            const unsigned short* wb = Wfrag + (size_t)((tap*3 + cc)*16)*512 + lane*8;
            #pragma unroll
            for (int g = 0; g < 4; ++g)
                bb[g] = *(const short8*)(wb + (size_t)(g*4 + w)*512);
            #pragma unroll
            for (int g = 0; g < 4; ++g)
                #pragma unroll
                for (int mf = 0; mf < 4; ++mf)
                    acc[g][mf] = __builtin_amdgcn_mfma_f32_16x16x32_bf16(
                                     a[mf], bb[g], acc[g][mf], 0, 0, 0);
        }
    }

    // ---- wave-local LSTM epilogue: lane(reg) holds (px, o) for all 4 gates
    const int o = w*16 + l15;
    const float bfv = bfp[o], biv = bip[o], bcv = bcp[o], bov = bop[o];
    #pragma unroll
    for (int mf = 0; mf < 4; ++mf){
        #pragma unroll
        for (int r = 0; r < 4; ++r){
            const int m = mf*16 + q*4 + r;                  // pixel x within the row
            const float fv = sigm_(acc[0][mf][r] + bfv);
            const float iv = sigm_(acc[1][mf][r] + biv);
            const float gv = tanh_(acc[2][mf][r] + bcv);
            const float ov = sigm_(acc[3][mf][r] + bov);
            const size_t cidx = (((size_t)b*HID_ + o)*H_ + y)*W_ + m;
            const float cprev = first ? 0.0f : c_in[cidx];
            const float cn = cprev*fv + iv*gv;
            const float hn = tanh_(cn)*ov;
            c_out[cidx] = cn;
            hbf_out[(((size_t)b*H_ + y)*W_ + m)*HID_ + o] = f2bf(hn);
            if (last) h_out[cidx] = hn;
        }
    }
}

extern "C" void kernel_launch(void* const* d_in, const int* in_sizes, int n_in,
                              void* d_out, int out_size, void* d_ws, size_t ws_size,
                              hipStream_t stream){
    const float* x  = (const float*)d_in[0];
    const float* Wf = (const float*)d_in[1];
    const float* bf = (const float*)d_in[2];
    const float* Wi = (const float*)d_in[3];
    const float* bi = (const float*)d_in[4];
    const float* Wc = (const float*)d_in[5];
    const float* bc = (const float*)d_in[6];
    const float* Wo = (const float*)d_in[7];
    const float* bo = (const float*)d_in[8];

    // ws: Wfrag 442368 B | cA 8388608 B | hbfA 4194304 B | hbfB 4194304 B  (16.4 MB)
    unsigned short* Wfrag = (unsigned short*)d_ws;
    float*          cA    = (float*)((char*)d_ws + 442368);
    unsigned short* hbfA  = (unsigned short*)((char*)d_ws + 442368 + 8388608);
    unsigned short* hbfB  = hbfA + CSTRIDE_;

    float* dout = (float*)d_out;
    float* cB   = dout + CSTRIDE_;       // c-region of d_out doubles as odd-step c buffer

    prep_wfrag<<<dim3(864), dim3(256), 0, stream>>>(Wf, Wi, Wc, Wo, Wfrag);

    dim3 grid(H_, B_);
    for (int t = 0; t < T_; ++t){
        const int first = (t == 0), last = (t == T_-1);
        float*                co = (t & 1) ? cB   : cA;
        const float*          ci = (t & 1) ? cA   : cB;
        unsigned short*       ho = (t & 1) ? hbfB : hbfA;
        const unsigned short* hi = (t & 1) ? hbfA : hbfB;
        lstm_step_mfma<<<grid, dim3(256), 0, stream>>>(
            x, ci, hi, Wfrag, co, ho, dout,
            bf, bi, bc, bo, t, first, last);
    }
}